// Round 8
// baseline (4649.404 us; speedup 1.0000x reference)
//
#include <hip/hip_runtime.h>
#include <math.h>
#include <stdint.h>
#include <stddef.h>

// ---------------------------------------------------------------------------
// Informer encoder forward (B=8, L=1024, C_IN=7, DM=512, H=8, DH=64, DFF=2048)
// Round 7: fp32 baseline. fill_idx now implements jax_threefry_partitionable
// semantics (default True in modern JAX):
//   key_l = threefry((0,42), (0,layer))                    [fold_in, unchanged]
//   split foldlike: k2 = threefry(key_l, (0,1))            [child index 1]
//   random_bits partitionable: elem j uses count (hi,lo)=(0,j);
//     bits32[j] = B1 ^ B2   (<=32-bit path XORs the two threefry outputs)
//   randint: multiplier = 2^32 % span = 0 -> idx[j] = bits32[j] & (Lk-1)
// LEDGER: legacy-split (r5/6) FAILED 1.295; legacy-noslpit (r3) FAILED 1.457.
// Both legacy streams wrong => partitionable mode. If this fails O(1.3):
// try bits=B1, then bits=B2.
// ---------------------------------------------------------------------------

#define DMODEL 512
#define NHEAD  8
#define DHEAD  64
#define NBATCH 8
#define NSAMP  35   // U = u = 5*ceil(ln(1024)) = 5*ceil(ln(512)) = 35

// ---------------- threefry2x32 (JAX-compatible) ----------------
__device__ __forceinline__ void threefry(uint32_t k0, uint32_t k1,
                                         uint32_t x0, uint32_t x1,
                                         uint32_t* o0, uint32_t* o1) {
  uint32_t ks0 = k0, ks1 = k1, ks2 = k0 ^ k1 ^ 0x1BD11BDAu;
  uint32_t a = x0 + k0, b = x1 + k1;
  const uint32_t rot0[4] = {13u, 15u, 26u, 6u};
  const uint32_t rot1[4] = {17u, 29u, 16u, 24u};
#pragma unroll
  for (int i = 0; i < 5; ++i) {
    const uint32_t* r = (i & 1) ? rot1 : rot0;
#pragma unroll
    for (int j = 0; j < 4; ++j) {
      a += b;
      b = (b << r[j]) | (b >> (32u - r[j]));
      b ^= a;
    }
    uint32_t ksA = ((i + 1) % 3 == 0) ? ks0 : (((i + 1) % 3 == 1) ? ks1 : ks2);
    uint32_t ksB = ((i + 2) % 3 == 0) ? ks0 : (((i + 2) % 3 == 1) ? ks1 : ks2);
    a += ksA;
    b += ksB + (uint32_t)(i + 1);
  }
  *o0 = a;
  *o1 = b;
}

// ---------------- block reduction helpers ----------------
__device__ __forceinline__ float block_sum(float v, float* red) {
#pragma unroll
  for (int off = 32; off > 0; off >>= 1) v += __shfl_down(v, off, 64);
  int lane = threadIdx.x & 63, wid = threadIdx.x >> 6, nw = blockDim.x >> 6;
  if (lane == 0) red[wid] = v;
  __syncthreads();
  if (threadIdx.x == 0) {
    float s = 0.f;
    for (int i = 0; i < nw; ++i) s += red[i];
    red[0] = s;
  }
  __syncthreads();
  float r = red[0];
  __syncthreads();
  return r;
}

__device__ __forceinline__ float block_max(float v, float* red) {
#pragma unroll
  for (int off = 32; off > 0; off >>= 1) v = fmaxf(v, __shfl_down(v, off, 64));
  int lane = threadIdx.x & 63, wid = threadIdx.x >> 6, nw = blockDim.x >> 6;
  if (lane == 0) red[wid] = v;
  __syncthreads();
  if (threadIdx.x == 0) {
    float s = -INFINITY;
    for (int i = 0; i < nw; ++i) s = fmaxf(s, red[i]);
    red[0] = s;
  }
  __syncthreads();
  float r = red[0];
  __syncthreads();
  return r;
}

// ---------------- token embedding: conv1d(k=3,7->512)+relu+LN, then 2h+PE ----
__global__ __launch_bounds__(512) void token_embed_kernel(
    const float* __restrict__ x, const float* __restrict__ tk,
    const float* __restrict__ tb, const float* __restrict__ g,
    const float* __restrict__ be, float* __restrict__ h) {
  int bl = blockIdx.x;            // b*1024 + l
  int b = bl >> 10, l = bl & 1023;
  __shared__ float xs[3][7];
  __shared__ float red[8];
  int tid = threadIdx.x;
  if (tid < 21) {
    int kw = tid / 7, i = tid % 7;
    int sl = l + kw - 1;
    xs[kw][i] = (sl >= 0 && sl < 1024) ? x[((size_t)b * 1024 + sl) * 7 + i] : 0.f;
  }
  __syncthreads();
  float s = tb[tid];
#pragma unroll
  for (int kw = 0; kw < 3; ++kw)
#pragma unroll
    for (int i = 0; i < 7; ++i)
      s = fmaf(xs[kw][i], tk[((kw * 7) + i) * DMODEL + tid], s);
  s = fmaxf(s, 0.f);
  // LayerNorm (two-pass, eps=1e-6)
  float mu = block_sum(s, red) * (1.f / 512.f);
  float d = s - mu;
  float var = block_sum(d * d, red) * (1.f / 512.f);
  float ln = g[tid] * d / sqrtf(var + 1e-6f) + be[tid];
  // positional encoding (interleaved sin/cos), h = 2*ln + pe
  float div = expf(-(float)(tid & ~1) * (9.2103403719761836f / 512.f));
  float ang = (float)l * div;
  float pe = (tid & 1) ? cosf(ang) : sinf(ang);
  h[(size_t)bl * DMODEL + tid] = 2.f * ln + pe;
}

// ---------------- generic tiled fp32 GEMM: C = A[M,K] @ W[K,N] + bias -------
// ACT: 0 = none, 1 = relu.  CONV3: A is [8, L=1024, 512] with k=3 SAME taps.
template <int ACT, int CONV3>
__global__ __launch_bounds__(256) void gemm_kernel(
    const float* __restrict__ A, const float* __restrict__ W,
    const float* __restrict__ bias, float* __restrict__ C,
    int M, int N, int K) {
  __shared__ float As[8][132];
  __shared__ float Ws[8][128];
  int tid = threadIdx.x;
  int tx = tid & 15, ty = tid >> 4;
  int m0 = blockIdx.y * 128, n0 = blockIdx.x * 128;
  float acc[8][8];
#pragma unroll
  for (int i = 0; i < 8; ++i)
#pragma unroll
    for (int j = 0; j < 8; ++j) acc[i][j] = 0.f;

  int ar = tid >> 1, ac = (tid & 1) * 4;
  int wr = tid >> 5, wc = (tid & 31) * 4;

  for (int kt = 0; kt < K; kt += 8) {
    float4 av;
    if (CONV3) {
      int kkg = kt + ac;            // 0..1535, all 4 lanes same kw
      int kw = kkg >> 9;
      int ch = kkg & 511;
      int rg = m0 + ar;
      int b = rg >> 10, l = rg & 1023;
      int sl = l + kw - 1;
      if (sl >= 0 && sl < 1024)
        av = *(const float4*)&A[(((size_t)b << 10) + sl) * DMODEL + ch];
      else
        av = make_float4(0.f, 0.f, 0.f, 0.f);
    } else {
      av = *(const float4*)&A[(size_t)(m0 + ar) * K + kt + ac];
    }
    float4 wv = *(const float4*)&W[(size_t)(kt + wr) * N + n0 + wc];
    As[ac + 0][ar] = av.x;
    As[ac + 1][ar] = av.y;
    As[ac + 2][ar] = av.z;
    As[ac + 3][ar] = av.w;
    *(float4*)&Ws[wr][wc] = wv;
    __syncthreads();
#pragma unroll
    for (int kk = 0; kk < 8; ++kk) {
      float a[8], bv[8];
      *(float4*)&a[0] = *(const float4*)&As[kk][ty * 8];
      *(float4*)&a[4] = *(const float4*)&As[kk][ty * 8 + 4];
      *(float4*)&bv[0] = *(const float4*)&Ws[kk][tx * 8];
      *(float4*)&bv[4] = *(const float4*)&Ws[kk][tx * 8 + 4];
#pragma unroll
      for (int i = 0; i < 8; ++i)
#pragma unroll
        for (int j = 0; j < 8; ++j) acc[i][j] = fmaf(a[i], bv[j], acc[i][j]);
    }
    __syncthreads();
  }
#pragma unroll
  for (int i = 0; i < 8; ++i) {
    size_t row = (size_t)(m0 + ty * 8 + i) * N + n0;
    float o[8];
#pragma unroll
    for (int j = 0; j < 8; ++j) {
      float v = acc[i][j] + bias[n0 + tx * 8 + j];
      if (ACT == 1) v = fmaxf(v, 0.f);
      o[j] = v;
    }
    *(float4*)&C[row + tx * 8] = make_float4(o[0], o[1], o[2], o[3]);
    *(float4*)&C[row + tx * 8 + 4] = make_float4(o[4], o[5], o[6], o[7]);
  }
}

// ---------------- residual + LayerNorm (r may be null) ----------------------
__global__ __launch_bounds__(512) void res_ln_kernel(
    const float* __restrict__ a, const float* __restrict__ r,
    const float* __restrict__ g, const float* __restrict__ be,
    float* __restrict__ out) {
  __shared__ float red[8];
  size_t row = blockIdx.x;
  int c = threadIdx.x;
  float v = a[row * DMODEL + c];
  if (r) v += r[row * DMODEL + c];
  float mu = block_sum(v, red) * (1.f / 512.f);
  float d = v - mu;
  float var = block_sum(d * d, red) * (1.f / 512.f);
  out[row * DMODEL + c] = g[c] * d / sqrtf(var + 1e-6f) + be[c];
}

// ---------------- idx: jax_threefry_partitionable randint ------------------
// key_l = fold_in(key(42), layer); k2 = threefry(key_l, (0,1)) [foldlike
// split child 1]; elem j: (B1,B2) = threefry(k2, (0,j));
// bits32 = B1 ^ B2; idx[j] = bits32 & (Lk-1)   (multiplier = 2^32 % span = 0)
__global__ void fill_idx_kernel(int* __restrict__ idx, int layer, int total,
                                int Lk) {
  int j = blockIdx.x * 256 + threadIdx.x;
  if (j >= total) return;
  uint32_t kl0, kl1, k20, k21;
  threefry(0u, 42u, 0u, (uint32_t)layer, &kl0, &kl1);   // fold_in(key(42), layer)
  threefry(kl0, kl1, 0u, 1u, &k20, &k21);               // foldlike split -> k2
  uint32_t b1, b2;
  threefry(k20, k21, 0u, (uint32_t)j, &b1, &b2);        // count64 = j -> (0, j)
  idx[j] = (int)((b1 ^ b2) & (uint32_t)(Lk - 1));
}

// ---------------- sparsity measure M = max - mean over sampled keys ---------
__global__ __launch_bounds__(256) void sample_m_kernel(
    const float* __restrict__ Q, const float* __restrict__ K,
    const int* __restrict__ idx, float* __restrict__ M, int L) {
  int wid = threadIdx.x >> 6, lane = threadIdx.x & 63;
  int g = blockIdx.x * 4 + wid;   // (b*8+h)*L + l
  int l = g % L;
  int bh = g / L;
  int h = bh & 7, b = bh >> 3;
  float mx = -INFINITY, sm = 0.f;
  if (lane < NSAMP) {
    int kl = idx[l * NSAMP + lane];
    const float* qr = Q + ((size_t)(b * L + l)) * DMODEL + h * DHEAD;
    const float* kr = K + ((size_t)(b * L + kl)) * DMODEL + h * DHEAD;
    float s = 0.f;
#pragma unroll
    for (int d = 0; d < DHEAD; d += 4) {
      float4 a = *(const float4*)(qr + d);
      float4 c = *(const float4*)(kr + d);
      s = fmaf(a.x, c.x, s);
      s = fmaf(a.y, c.y, s);
      s = fmaf(a.z, c.z, s);
      s = fmaf(a.w, c.w, s);
    }
    mx = s;
    sm = s;
  }
#pragma unroll
  for (int off = 32; off > 0; off >>= 1) {
    mx = fmaxf(mx, __shfl_down(mx, off, 64));
    sm += __shfl_down(sm, off, 64);
  }
  if (lane == 0) M[g] = mx - sm * (1.f / (float)NSAMP);
}

// ---------------- top-35 per (b,h), ties -> lower index (lax.top_k) ---------
__global__ __launch_bounds__(256) void topk_kernel(const float* __restrict__ M,
                                                   int* __restrict__ top, int L) {
  __shared__ float vals[1024];
  __shared__ float rv[256];
  __shared__ int ri[256];
  int bh = blockIdx.x;
  const float* m = M + (size_t)bh * L;
  for (int i = threadIdx.x; i < L; i += 256) vals[i] = m[i];
  __syncthreads();
  for (int it = 0; it < NSAMP; ++it) {
    float bv = -INFINITY;
    int bi = 0x7fffffff;
    for (int i = threadIdx.x; i < L; i += 256) {
      float v = vals[i];
      if (v > bv || (v == bv && i < bi)) { bv = v; bi = i; }
    }
    rv[threadIdx.x] = bv;
    ri[threadIdx.x] = bi;
    __syncthreads();
    for (int s = 128; s > 0; s >>= 1) {
      if (threadIdx.x < s) {
        float ov = rv[threadIdx.x + s];
        int oi = ri[threadIdx.x + s];
        if (ov > rv[threadIdx.x] ||
            (ov == rv[threadIdx.x] && oi < ri[threadIdx.x])) {
          rv[threadIdx.x] = ov;
          ri[threadIdx.x] = oi;
        }
      }
      __syncthreads();
    }
    if (threadIdx.x == 0) {
      top[bh * NSAMP + it] = ri[0];
      vals[ri[0]] = -INFINITY;
    }
    __syncthreads();
  }
}

// ---------------- mean of V over L per (b,h,d) ------------------------------
__global__ __launch_bounds__(64) void meanv_kernel(const float* __restrict__ V,
                                                   float* __restrict__ mv, int L) {
  int bh = blockIdx.x;
  int h = bh & 7, b = bh >> 3;
  int d = threadIdx.x;
  const float* vb = V + (size_t)b * L * DMODEL + h * DHEAD + d;
  float s = 0.f;
  for (int l = 0; l < L; ++l) s += vb[(size_t)l * DMODEL];
  mv[bh * DHEAD + d] = s / (float)L;
}

// ---------------- ctx[b,l,c] = meanV[b,c] broadcast -------------------------
__global__ __launch_bounds__(256) void ctx_fill_kernel(
    const float* __restrict__ mv, float* __restrict__ ctx, int L) {
  int i = blockIdx.x * 256 + threadIdx.x;
  int c = i & 511;
  int b = i / (L * DMODEL);
  ctx[i] = mv[b * DMODEL + c];
}

// ---------------- full attention for the top-35 queries ---------------------
__global__ __launch_bounds__(256) void attn_top_kernel(
    const float* __restrict__ Q, const float* __restrict__ K,
    const float* __restrict__ V, const int* __restrict__ top,
    float* __restrict__ ctx, int L) {
  __shared__ float qs[64];
  __shared__ float sc[1024];
  __shared__ float red[8];
  __shared__ float outp[4][64];
  int ui = blockIdx.x % NSAMP;
  int bh = blockIdx.x / NSAMP;
  int h = bh & 7, b = bh >> 3;
  int tid = threadIdx.x;
  int tl = top[bh * NSAMP + ui];
  const float* qr = Q + ((size_t)(b * L + tl)) * DMODEL + h * DHEAD;
  if (tid < 64) qs[tid] = qr[tid];
  __syncthreads();
  float lmax = -INFINITY;
  for (int kk = tid; kk < L; kk += 256) {
    const float* kr = K + ((size_t)(b * L + kk)) * DMODEL + h * DHEAD;
    float s = 0.f;
#pragma unroll
    for (int d = 0; d < DHEAD; d += 4) {
      float4 kq = *(const float4*)(kr + d);
      float4 qq = *(const float4*)(qs + d);
      s = fmaf(kq.x, qq.x, s);
      s = fmaf(kq.y, qq.y, s);
      s = fmaf(kq.z, qq.z, s);
      s = fmaf(kq.w, qq.w, s);
    }
    s *= 0.125f;   // 1/sqrt(64)
    sc[kk] = s;
    lmax = fmaxf(lmax, s);
  }
  float bmax = block_max(lmax, red);
  float lsum = 0.f;
  for (int kk = tid; kk < L; kk += 256) {
    float p = expf(sc[kk] - bmax);
    sc[kk] = p;
    lsum += p;
  }
  float bsum = block_sum(lsum, red);
  int d = tid & 63, part = tid >> 6;
  int chunk = L >> 2;
  const float* vb = V + (size_t)b * L * DMODEL + h * DHEAD + d;
  float acc = 0.f;
  for (int kk = part * chunk; kk < (part + 1) * chunk; ++kk)
    acc = fmaf(sc[kk], vb[(size_t)kk * DMODEL], acc);
  outp[part][d] = acc;
  __syncthreads();
  if (tid < 64) {
    float o = (outp[0][tid] + outp[1][tid] + outp[2][tid] + outp[3][tid]) / bsum;
    ctx[((size_t)(b * L + tl)) * DMODEL + h * DHEAD + tid] = o;
  }
}

// ---------------- ELU(maxpool3,s2,SAME) (ELU monotone -> pool first) --------
__global__ __launch_bounds__(256) void elu_pool_kernel(
    const float* __restrict__ cin, float* __restrict__ out, int Lin) {
  int Lout = Lin >> 1;
  int i = blockIdx.x * 256 + threadIdx.x;
  int c = i & 511;
  int w = (i >> 9) % Lout;
  int b = i / (Lout * DMODEL);
  int l0 = 2 * w;
  const float* base = cin + ((size_t)b * Lin) * DMODEL + c;
  float m = base[(size_t)l0 * DMODEL];
  m = fmaxf(m, base[(size_t)(l0 + 1) * DMODEL]);
  if (l0 + 2 < Lin) m = fmaxf(m, base[(size_t)(l0 + 2) * DMODEL]);
  out[i] = (m > 0.f) ? m : expm1f(m);
}

// ---------------------------------------------------------------------------
extern "C" void kernel_launch(void* const* d_in, const int* in_sizes, int n_in,
                              void* d_out, int out_size, void* d_ws,
                              size_t ws_size, hipStream_t stream) {
  (void)in_sizes; (void)n_in; (void)out_size; (void)ws_size;
  const float* x       = (const float*)d_in[0];
  const float* tok_k   = (const float*)d_in[1];
  const float* tok_b   = (const float*)d_in[2];
  const float* tok_g   = (const float*)d_in[3];
  const float* tok_be  = (const float*)d_in[4];
  const float* Wq      = (const float*)d_in[5];
  const float* bq      = (const float*)d_in[6];
  const float* Wk      = (const float*)d_in[7];
  const float* bk      = (const float*)d_in[8];
  const float* Wv      = (const float*)d_in[9];
  const float* bv      = (const float*)d_in[10];
  const float* Wo      = (const float*)d_in[11];
  const float* bo      = (const float*)d_in[12];
  const float* ln1_g   = (const float*)d_in[13];
  const float* ln1_b   = (const float*)d_in[14];
  const float* ln2_g   = (const float*)d_in[15];
  const float* ln2_b   = (const float*)d_in[16];
  const float* w1      = (const float*)d_in[17];
  const float* b1      = (const float*)d_in[18];
  const float* w2      = (const float*)d_in[19];
  const float* b2      = (const float*)d_in[20];
  const float* dconv_k = (const float*)d_in[21];
  const float* dconv_b = (const float*)d_in[22];
  const float* nf_g    = (const float*)d_in[23];
  const float* nf_b    = (const float*)d_in[24];

  float* ws = (float*)d_ws;
  const size_t SZ = (size_t)NBATCH * 1024 * DMODEL;  // 4,194,304 floats
  float* hb   = ws + 0 * SZ;
  float* qb   = ws + 1 * SZ;
  float* kb   = ws + 2 * SZ;
  float* vb   = ws + 3 * SZ;
  float* ctxb = ws + 4 * SZ;
  float* t5   = ws + 5 * SZ;
  float* midb = ws + 6 * SZ;                // FFN mid chunk (2048x2048)
  // attention scratch overlaid on midb (phases are disjoint)
  float* Mb   = midb;                       // 65536
  int*   topb = (int*)(midb + 65536);       // 2240
  int*   idxb = (int*)(midb + 68096);       // 35840
  float* mvb  = midb + 104448;              // 4096

  auto enc_layer = [&](int layer, int L) {
    int BL = NBATCH * L;
    // Q/K/V projections
    gemm_kernel<0, 0><<<dim3(4, BL / 128), 256, 0, stream>>>(
        hb, Wq + (size_t)layer * 262144, bq + layer * 512, qb, BL, 512, 512);
    gemm_kernel<0, 0><<<dim3(4, BL / 128), 256, 0, stream>>>(
        hb, Wk + (size_t)layer * 262144, bk + layer * 512, kb, BL, 512, 512);
    gemm_kernel<0, 0><<<dim3(4, BL / 128), 256, 0, stream>>>(
        hb, Wv + (size_t)layer * 262144, bv + layer * 512, vb, BL, 512, 512);
    // ProbSparse attention
    int total = L * NSAMP;
    fill_idx_kernel<<<(total + 255) / 256, 256, 0, stream>>>(idxb, layer,
                                                             total, L);
    sample_m_kernel<<<(64 * L) / 4, 256, 0, stream>>>(qb, kb, idxb, Mb, L);
    topk_kernel<<<64, 256, 0, stream>>>(Mb, topb, L);
    meanv_kernel<<<64, 64, 0, stream>>>(vb, mvb, L);
    ctx_fill_kernel<<<(BL * DMODEL) / 256, 256, 0, stream>>>(mvb, ctxb, L);
    attn_top_kernel<<<64 * NSAMP, 256, 0, stream>>>(qb, kb, vb, topb, ctxb, L);
    // O projection -> t5 ; x1 = LN(h + attn_out) -> ctxb
    gemm_kernel<0, 0><<<dim3(4, BL / 128), 256, 0, stream>>>(
        ctxb, Wo + (size_t)layer * 262144, bo + layer * 512, t5, BL, 512, 512);
    res_ln_kernel<<<BL, 512, 0, stream>>>(hb, t5, ln1_g + layer * 512,
                                          ln1_b + layer * 512, ctxb);
    // FFN (row-chunked to keep mid buffer at 16 MB)
    for (int r0 = 0; r0 < BL; r0 += 2048) {
      gemm_kernel<1, 0><<<dim3(16, 16), 256, 0, stream>>>(
          ctxb + (size_t)r0 * 512, w1 + (size_t)layer * 1048576,
          b1 + layer * 2048, midb, 2048, 2048, 512);
      gemm_kernel<0, 0><<<dim3(4, 16), 256, 0, stream>>>(
          midb, w2 + (size_t)layer * 1048576, b2 + layer * 512,
          t5 + (size_t)r0 * 512, 2048, 512, 2048);
    }
    // x2 = LN(x1 + y) -> hb
    res_ln_kernel<<<BL, 512, 0, stream>>>(ctxb, t5, ln2_g + layer * 512,
                                          ln2_b + layer * 512, hb);
  };

  // Stage 1+2: token embedding + LN + (2h + PE)
  token_embed_kernel<<<NBATCH * 1024, 512, 0, stream>>>(x, tok_k, tok_b, tok_g,
                                                        tok_be, hb);
  // Encoder layer 0 (L=1024)
  enc_layer(0, 1024);
  // Distilling: conv1d(k=3,512->512)+bias -> qb ; ELU(maxpool) -> hb [8,512,512]
  gemm_kernel<0, 1><<<dim3(4, 64), 256, 0, stream>>>(hb, dconv_k, dconv_b, qb,
                                                     8192, 512, 1536);
  elu_pool_kernel<<<(NBATCH * 512 * DMODEL) / 256, 256, 0, stream>>>(qb, hb,
                                                                     1024);
  // Encoder layer 1 (L=512)
  enc_layer(1, 512);
  // Final LayerNorm -> d_out
  res_ln_kernel<<<NBATCH * 512, 512, 0, stream>>>(hb, nullptr, nf_g, nf_b,
                                                  (float*)d_out);
}

// Round 10
// 2144.037 us; speedup vs baseline: 2.1685x; 2.1685x over previous
//
#include <hip/hip_runtime.h>
#include <math.h>
#include <stdint.h>
#include <stddef.h>

// ---------------------------------------------------------------------------
// Informer encoder forward (B=8, L=1024, C_IN=7, DM=512, H=8, DH=64, DFF=2048)
// Round 9: resubmit of round-8 retile (GPU timed out; desk-audited OK).
// vs 4649us PASSED baseline: occupancy-driven GEMM retile. Counters showed
// GEMMs latency-bound: 256 blocks = 1 wave/SIMD, VALUBusy 8%, Occupancy 3%,
// LDS conflicts 4.2M. Fix: BM in {128,64} x BN=64, BK=16, 256 thr -> all GEMM
// grids >= 512 blocks; 16B-stride LDS reads (2-way = free); same k-order =>
// bitwise-same output. meanv parallelized. FFN M=4096 chunks, mid on qb+kb.
// PRNG LEDGER (HW-verified): jax_threefry_partitionable semantics CONFIRMED:
//   k2 = threefry(key_l,(0,1)); bits[j] = xor(threefry(k2,(0,j))); idx=&(Lk-1)
//   (legacy-split FAILED 1.295, legacy-nosplit FAILED 1.457, this PASSED)
// ---------------------------------------------------------------------------

#define DMODEL 512
#define NHEAD  8
#define DHEAD  64
#define NBATCH 8
#define NSAMP  35   // U = u = 5*ceil(ln(1024)) = 5*ceil(ln(512)) = 35

// ---------------- threefry2x32 (JAX-compatible) ----------------
__device__ __forceinline__ void threefry(uint32_t k0, uint32_t k1,
                                         uint32_t x0, uint32_t x1,
                                         uint32_t* o0, uint32_t* o1) {
  uint32_t ks0 = k0, ks1 = k1, ks2 = k0 ^ k1 ^ 0x1BD11BDAu;
  uint32_t a = x0 + k0, b = x1 + k1;
  const uint32_t rot0[4] = {13u, 15u, 26u, 6u};
  const uint32_t rot1[4] = {17u, 29u, 16u, 24u};
#pragma unroll
  for (int i = 0; i < 5; ++i) {
    const uint32_t* r = (i & 1) ? rot1 : rot0;
#pragma unroll
    for (int j = 0; j < 4; ++j) {
      a += b;
      b = (b << r[j]) | (b >> (32u - r[j]));
      b ^= a;
    }
    uint32_t ksA = ((i + 1) % 3 == 0) ? ks0 : (((i + 1) % 3 == 1) ? ks1 : ks2);
    uint32_t ksB = ((i + 2) % 3 == 0) ? ks0 : (((i + 2) % 3 == 1) ? ks1 : ks2);
    a += ksA;
    b += ksB + (uint32_t)(i + 1);
  }
  *o0 = a;
  *o1 = b;
}

// ---------------- block reduction helpers ----------------
__device__ __forceinline__ float block_sum(float v, float* red) {
#pragma unroll
  for (int off = 32; off > 0; off >>= 1) v += __shfl_down(v, off, 64);
  int lane = threadIdx.x & 63, wid = threadIdx.x >> 6, nw = blockDim.x >> 6;
  if (lane == 0) red[wid] = v;
  __syncthreads();
  if (threadIdx.x == 0) {
    float s = 0.f;
    for (int i = 0; i < nw; ++i) s += red[i];
    red[0] = s;
  }
  __syncthreads();
  float r = red[0];
  __syncthreads();
  return r;
}

__device__ __forceinline__ float block_max(float v, float* red) {
#pragma unroll
  for (int off = 32; off > 0; off >>= 1) v = fmaxf(v, __shfl_down(v, off, 64));
  int lane = threadIdx.x & 63, wid = threadIdx.x >> 6, nw = blockDim.x >> 6;
  if (lane == 0) red[wid] = v;
  __syncthreads();
  if (threadIdx.x == 0) {
    float s = -INFINITY;
    for (int i = 0; i < nw; ++i) s = fmaxf(s, red[i]);
    red[0] = s;
  }
  __syncthreads();
  float r = red[0];
  __syncthreads();
  return r;
}

// ---------------- token embedding: conv1d(k=3,7->512)+relu+LN, then 2h+PE ----
__global__ __launch_bounds__(512) void token_embed_kernel(
    const float* __restrict__ x, const float* __restrict__ tk,
    const float* __restrict__ tb, const float* __restrict__ g,
    const float* __restrict__ be, float* __restrict__ h) {
  int bl = blockIdx.x;            // b*1024 + l
  int b = bl >> 10, l = bl & 1023;
  __shared__ float xs[3][7];
  __shared__ float red[8];
  int tid = threadIdx.x;
  if (tid < 21) {
    int kw = tid / 7, i = tid % 7;
    int sl = l + kw - 1;
    xs[kw][i] = (sl >= 0 && sl < 1024) ? x[((size_t)b * 1024 + sl) * 7 + i] : 0.f;
  }
  __syncthreads();
  float s = tb[tid];
#pragma unroll
  for (int kw = 0; kw < 3; ++kw)
#pragma unroll
    for (int i = 0; i < 7; ++i)
      s = fmaf(xs[kw][i], tk[((kw * 7) + i) * DMODEL + tid], s);
  s = fmaxf(s, 0.f);
  // LayerNorm (two-pass, eps=1e-6)
  float mu = block_sum(s, red) * (1.f / 512.f);
  float d = s - mu;
  float var = block_sum(d * d, red) * (1.f / 512.f);
  float ln = g[tid] * d / sqrtf(var + 1e-6f) + be[tid];
  // positional encoding (interleaved sin/cos), h = 2*ln + pe
  float div = expf(-(float)(tid & ~1) * (9.2103403719761836f / 512.f));
  float ang = (float)l * div;
  float pe = (tid & 1) ? cosf(ang) : sinf(ang);
  h[(size_t)bl * DMODEL + tid] = 2.f * ln + pe;
}

// ---------------- tiled fp32 GEMM: C = A[M,K] @ W[K,N] + bias ---------------
// BN=64, BK=16, 256 threads, TN=4, TM=BM/16 (BM in {128, 64}).
// ACT: 1 = relu. CONV3: A is [8,1024,512], K=1536 over k=3 SAME taps.
template <int BM, int ACT, int CONV3>
__global__ __launch_bounds__(256) void gemm_kernel(
    const float* __restrict__ A, const float* __restrict__ W,
    const float* __restrict__ bias, float* __restrict__ C,
    int M, int N, int K) {
  constexpr int TM = BM / 16;        // 8 or 4 rows per thread
  constexpr int TPR = 16 / TM;       // threads per A-row slice (2 or 4)
  __shared__ float As[16][BM + 4];
  __shared__ float Ws[16][68];
  int tid = threadIdx.x;
  int tx = tid & 15, ty = tid >> 4;
  int m0 = blockIdx.y * BM, n0 = blockIdx.x * 64;
  float acc[TM][4];
#pragma unroll
  for (int i = 0; i < TM; ++i)
#pragma unroll
    for (int j = 0; j < 4; ++j) acc[i][j] = 0.f;

  int ar = tid / TPR;                // A row in tile [0, BM)
  int ac = (tid % TPR) * TM;         // A k-col base in tile [0,16), TM-aligned
  int wr = tid >> 4, wc = (tid & 15) * 4;

  for (int kt = 0; kt < K; kt += 16) {
    // ---- stage A (BM x 16, stored transposed As[k][m]) ----
    float av[TM];
    if (CONV3) {
      // k-group of TM floats is 4/8-aligned; never crosses a 512 boundary
      int kkg = kt + ac;
      int kw = kkg >> 9;
      int ch = kkg & 511;
      int rg = m0 + ar;
      int b = rg >> 10, l = rg & 1023;
      int sl = l + kw - 1;
      if (sl >= 0 && sl < 1024) {
#pragma unroll
        for (int t = 0; t < TM; t += 4)
          *(float4*)&av[t] =
              *(const float4*)&A[(((size_t)b << 10) + sl) * DMODEL + ch + t];
      } else {
#pragma unroll
        for (int t = 0; t < TM; ++t) av[t] = 0.f;
      }
    } else {
#pragma unroll
      for (int t = 0; t < TM; t += 4)
        *(float4*)&av[t] = *(const float4*)&A[(size_t)(m0 + ar) * K + kt + ac + t];
    }
#pragma unroll
    for (int t = 0; t < TM; ++t) As[ac + t][ar] = av[t];
    // ---- stage W (16 x 64) ----
    *(float4*)&Ws[wr][wc] = *(const float4*)&W[(size_t)(kt + wr) * N + n0 + wc];
    __syncthreads();
    // ---- compute ----
#pragma unroll
    for (int kk = 0; kk < 16; ++kk) {
      float b4[4], a[TM];
      *(float4*)b4 = *(const float4*)&Ws[kk][tx * 4];
#pragma unroll
      for (int t = 0; t < TM; t += 4)
        *(float4*)&a[t] = *(const float4*)&As[kk][ty * TM + t];
#pragma unroll
      for (int i = 0; i < TM; ++i)
#pragma unroll
        for (int j = 0; j < 4; ++j) acc[i][j] = fmaf(a[i], b4[j], acc[i][j]);
    }
    __syncthreads();
  }
  // ---- epilogue ----
#pragma unroll
  for (int i = 0; i < TM; ++i) {
    size_t row = (size_t)(m0 + ty * TM + i) * N + n0;
    float o[4];
#pragma unroll
    for (int j = 0; j < 4; ++j) {
      float v = acc[i][j] + bias[n0 + tx * 4 + j];
      if (ACT == 1) v = fmaxf(v, 0.f);
      o[j] = v;
    }
    *(float4*)&C[row + tx * 4] = make_float4(o[0], o[1], o[2], o[3]);
  }
}

// ---------------- residual + LayerNorm (r may be null) ----------------------
__global__ __launch_bounds__(512) void res_ln_kernel(
    const float* __restrict__ a, const float* __restrict__ r,
    const float* __restrict__ g, const float* __restrict__ be,
    float* __restrict__ out) {
  __shared__ float red[8];
  size_t row = blockIdx.x;
  int c = threadIdx.x;
  float v = a[row * DMODEL + c];
  if (r) v += r[row * DMODEL + c];
  float mu = block_sum(v, red) * (1.f / 512.f);
  float d = v - mu;
  float var = block_sum(d * d, red) * (1.f / 512.f);
  out[row * DMODEL + c] = g[c] * d / sqrtf(var + 1e-6f) + be[c];
}

// ---------------- idx: jax_threefry_partitionable randint (HW-VERIFIED) ----
__global__ void fill_idx_kernel(int* __restrict__ idx, int layer, int total,
                                int Lk) {
  int j = blockIdx.x * 256 + threadIdx.x;
  if (j >= total) return;
  uint32_t kl0, kl1, k20, k21;
  threefry(0u, 42u, 0u, (uint32_t)layer, &kl0, &kl1);   // fold_in(key(42), layer)
  threefry(kl0, kl1, 0u, 1u, &k20, &k21);               // foldlike split -> k2
  uint32_t b1, b2;
  threefry(k20, k21, 0u, (uint32_t)j, &b1, &b2);        // count64 = (0, j)
  idx[j] = (int)((b1 ^ b2) & (uint32_t)(Lk - 1));
}

// ---------------- sparsity measure M = max - mean over sampled keys ---------
__global__ __launch_bounds__(256) void sample_m_kernel(
    const float* __restrict__ Q, const float* __restrict__ K,
    const int* __restrict__ idx, float* __restrict__ M, int L) {
  int wid = threadIdx.x >> 6, lane = threadIdx.x & 63;
  int g = blockIdx.x * 4 + wid;   // (b*8+h)*L + l
  int l = g % L;
  int bh = g / L;
  int h = bh & 7, b = bh >> 3;
  float mx = -INFINITY, sm = 0.f;
  if (lane < NSAMP) {
    int kl = idx[l * NSAMP + lane];
    const float* qr = Q + ((size_t)(b * L + l)) * DMODEL + h * DHEAD;
    const float* kr = K + ((size_t)(b * L + kl)) * DMODEL + h * DHEAD;
    float s = 0.f;
#pragma unroll
    for (int d = 0; d < DHEAD; d += 4) {
      float4 a = *(const float4*)(qr + d);
      float4 c = *(const float4*)(kr + d);
      s = fmaf(a.x, c.x, s);
      s = fmaf(a.y, c.y, s);
      s = fmaf(a.z, c.z, s);
      s = fmaf(a.w, c.w, s);
    }
    mx = s;
    sm = s;
  }
#pragma unroll
  for (int off = 32; off > 0; off >>= 1) {
    mx = fmaxf(mx, __shfl_down(mx, off, 64));
    sm += __shfl_down(sm, off, 64);
  }
  if (lane == 0) M[g] = mx - sm * (1.f / (float)NSAMP);
}

// ---------------- top-35 per (b,h), ties -> lower index (lax.top_k) ---------
__global__ __launch_bounds__(256) void topk_kernel(const float* __restrict__ M,
                                                   int* __restrict__ top, int L) {
  __shared__ float vals[1024];
  __shared__ float rv[256];
  __shared__ int ri[256];
  int bh = blockIdx.x;
  const float* m = M + (size_t)bh * L;
  for (int i = threadIdx.x; i < L; i += 256) vals[i] = m[i];
  __syncthreads();
  for (int it = 0; it < NSAMP; ++it) {
    float bv = -INFINITY;
    int bi = 0x7fffffff;
    for (int i = threadIdx.x; i < L; i += 256) {
      float v = vals[i];
      if (v > bv || (v == bv && i < bi)) { bv = v; bi = i; }
    }
    rv[threadIdx.x] = bv;
    ri[threadIdx.x] = bi;
    __syncthreads();
    for (int s = 128; s > 0; s >>= 1) {
      if (threadIdx.x < s) {
        float ov = rv[threadIdx.x + s];
        int oi = ri[threadIdx.x + s];
        if (ov > rv[threadIdx.x] ||
            (ov == rv[threadIdx.x] && oi < ri[threadIdx.x])) {
          rv[threadIdx.x] = ov;
          ri[threadIdx.x] = oi;
        }
      }
      __syncthreads();
    }
    if (threadIdx.x == 0) {
      top[bh * NSAMP + it] = ri[0];
      vals[ri[0]] = -INFINITY;
    }
    __syncthreads();
  }
}

// ---------------- mean of V over L per (b,h,d): 256 thr, 4-way L split ------
__global__ __launch_bounds__(256) void meanv_kernel(const float* __restrict__ V,
                                                    float* __restrict__ mv, int L) {
  __shared__ float part[4][64];
  int bh = blockIdx.x;
  int h = bh & 7, b = bh >> 3;
  int d = threadIdx.x & 63, p = threadIdx.x >> 6;
  int chunk = L >> 2;
  const float* vb = V + (size_t)b * L * DMODEL + h * DHEAD + d;
  float s = 0.f;
  for (int l = p * chunk; l < (p + 1) * chunk; ++l) s += vb[(size_t)l * DMODEL];
  part[p][d] = s;
  __syncthreads();
  if (threadIdx.x < 64) {
    float t = part[0][d] + part[1][d] + part[2][d] + part[3][d];
    mv[bh * DHEAD + d] = t / (float)L;
  }
}

// ---------------- ctx[b,l,c] = meanV[b,c] broadcast -------------------------
__global__ __launch_bounds__(256) void ctx_fill_kernel(
    const float* __restrict__ mv, float* __restrict__ ctx, int L) {
  int i = blockIdx.x * 256 + threadIdx.x;
  int c = i & 511;
  int b = i / (L * DMODEL);
  ctx[i] = mv[b * DMODEL + c];
}

// ---------------- full attention for the top-35 queries ---------------------
__global__ __launch_bounds__(256) void attn_top_kernel(
    const float* __restrict__ Q, const float* __restrict__ K,
    const float* __restrict__ V, const int* __restrict__ top,
    float* __restrict__ ctx, int L) {
  __shared__ float qs[64];
  __shared__ float sc[1024];
  __shared__ float red[8];
  __shared__ float outp[4][64];
  int ui = blockIdx.x % NSAMP;
  int bh = blockIdx.x / NSAMP;
  int h = bh & 7, b = bh >> 3;
  int tid = threadIdx.x;
  int tl = top[bh * NSAMP + ui];
  const float* qr = Q + ((size_t)(b * L + tl)) * DMODEL + h * DHEAD;
  if (tid < 64) qs[tid] = qr[tid];
  __syncthreads();
  float lmax = -INFINITY;
  for (int kk = tid; kk < L; kk += 256) {
    const float* kr = K + ((size_t)(b * L + kk)) * DMODEL + h * DHEAD;
    float s = 0.f;
#pragma unroll
    for (int d = 0; d < DHEAD; d += 4) {
      float4 kq = *(const float4*)(kr + d);
      float4 qq = *(const float4*)(qs + d);
      s = fmaf(kq.x, qq.x, s);
      s = fmaf(kq.y, qq.y, s);
      s = fmaf(kq.z, qq.z, s);
      s = fmaf(kq.w, qq.w, s);
    }
    s *= 0.125f;   // 1/sqrt(64)
    sc[kk] = s;
    lmax = fmaxf(lmax, s);
  }
  float bmax = block_max(lmax, red);
  float lsum = 0.f;
  for (int kk = tid; kk < L; kk += 256) {
    float p = expf(sc[kk] - bmax);
    sc[kk] = p;
    lsum += p;
  }
  float bsum = block_sum(lsum, red);
  int d = tid & 63, part = tid >> 6;
  int chunk = L >> 2;
  const float* vb = V + (size_t)b * L * DMODEL + h * DHEAD + d;
  float acc = 0.f;
  for (int kk = part * chunk; kk < (part + 1) * chunk; ++kk)
    acc = fmaf(sc[kk], vb[(size_t)kk * DMODEL], acc);
  outp[part][d] = acc;
  __syncthreads();
  if (tid < 64) {
    float o = (outp[0][tid] + outp[1][tid] + outp[2][tid] + outp[3][tid]) / bsum;
    ctx[((size_t)(b * L + tl)) * DMODEL + h * DHEAD + tid] = o;
  }
}

// ---------------- ELU(maxpool3,s2,SAME) (ELU monotone -> pool first) --------
__global__ __launch_bounds__(256) void elu_pool_kernel(
    const float* __restrict__ cin, float* __restrict__ out, int Lin) {
  int Lout = Lin >> 1;
  int i = blockIdx.x * 256 + threadIdx.x;
  int c = i & 511;
  int w = (i >> 9) % Lout;
  int b = i / (Lout * DMODEL);
  int l0 = 2 * w;
  const float* base = cin + ((size_t)b * Lin) * DMODEL + c;
  float m = base[(size_t)l0 * DMODEL];
  m = fmaxf(m, base[(size_t)(l0 + 1) * DMODEL]);
  if (l0 + 2 < Lin) m = fmaxf(m, base[(size_t)(l0 + 2) * DMODEL]);
  out[i] = (m > 0.f) ? m : expm1f(m);
}

// ---------------------------------------------------------------------------
extern "C" void kernel_launch(void* const* d_in, const int* in_sizes, int n_in,
                              void* d_out, int out_size, void* d_ws,
                              size_t ws_size, hipStream_t stream) {
  (void)in_sizes; (void)n_in; (void)out_size; (void)ws_size;
  const float* x       = (const float*)d_in[0];
  const float* tok_k   = (const float*)d_in[1];
  const float* tok_b   = (const float*)d_in[2];
  const float* tok_g   = (const float*)d_in[3];
  const float* tok_be  = (const float*)d_in[4];
  const float* Wq      = (const float*)d_in[5];
  const float* bq      = (const float*)d_in[6];
  const float* Wk      = (const float*)d_in[7];
  const float* bk      = (const float*)d_in[8];
  const float* Wv      = (const float*)d_in[9];
  const float* bv      = (const float*)d_in[10];
  const float* Wo      = (const float*)d_in[11];
  const float* bo      = (const float*)d_in[12];
  const float* ln1_g   = (const float*)d_in[13];
  const float* ln1_b   = (const float*)d_in[14];
  const float* ln2_g   = (const float*)d_in[15];
  const float* ln2_b   = (const float*)d_in[16];
  const float* w1      = (const float*)d_in[17];
  const float* b1      = (const float*)d_in[18];
  const float* w2      = (const float*)d_in[19];
  const float* b2      = (const float*)d_in[20];
  const float* dconv_k = (const float*)d_in[21];
  const float* dconv_b = (const float*)d_in[22];
  const float* nf_g    = (const float*)d_in[23];
  const float* nf_b    = (const float*)d_in[24];

  float* ws = (float*)d_ws;
  const size_t SZ = (size_t)NBATCH * 1024 * DMODEL;  // 4,194,304 floats
  float* hb   = ws + 0 * SZ;
  float* qb   = ws + 1 * SZ;   // also FFN mid (spans qb+kb = 32MB, dead then)
  float* kb   = ws + 2 * SZ;
  float* vb   = ws + 3 * SZ;
  float* ctxb = ws + 4 * SZ;
  float* t5   = ws + 5 * SZ;
  float* midb = ws + 6 * SZ;                // attention scratch region
  float* Mb   = midb;                       // 65536
  int*   topb = (int*)(midb + 65536);       // 2240
  int*   idxb = (int*)(midb + 68096);       // 35840
  float* mvb  = midb + 104448;              // 4096

  auto enc_layer = [&](int layer, int L) {
    int BL = NBATCH * L;
    // Q/K/V projections (BM=128 when BL=8192 -> 512 blocks; BM=64 when 4096)
    if (BL >= 8192) {
      gemm_kernel<128, 0, 0><<<dim3(8, BL / 128), 256, 0, stream>>>(
          hb, Wq + (size_t)layer * 262144, bq + layer * 512, qb, BL, 512, 512);
      gemm_kernel<128, 0, 0><<<dim3(8, BL / 128), 256, 0, stream>>>(
          hb, Wk + (size_t)layer * 262144, bk + layer * 512, kb, BL, 512, 512);
      gemm_kernel<128, 0, 0><<<dim3(8, BL / 128), 256, 0, stream>>>(
          hb, Wv + (size_t)layer * 262144, bv + layer * 512, vb, BL, 512, 512);
    } else {
      gemm_kernel<64, 0, 0><<<dim3(8, BL / 64), 256, 0, stream>>>(
          hb, Wq + (size_t)layer * 262144, bq + layer * 512, qb, BL, 512, 512);
      gemm_kernel<64, 0, 0><<<dim3(8, BL / 64), 256, 0, stream>>>(
          hb, Wk + (size_t)layer * 262144, bk + layer * 512, kb, BL, 512, 512);
      gemm_kernel<64, 0, 0><<<dim3(8, BL / 64), 256, 0, stream>>>(
          hb, Wv + (size_t)layer * 262144, bv + layer * 512, vb, BL, 512, 512);
    }
    // ProbSparse attention
    int total = L * NSAMP;
    fill_idx_kernel<<<(total + 255) / 256, 256, 0, stream>>>(idxb, layer,
                                                             total, L);
    sample_m_kernel<<<(64 * L) / 4, 256, 0, stream>>>(qb, kb, idxb, Mb, L);
    topk_kernel<<<64, 256, 0, stream>>>(Mb, topb, L);
    meanv_kernel<<<64, 256, 0, stream>>>(vb, mvb, L);
    ctx_fill_kernel<<<(BL * DMODEL) / 256, 256, 0, stream>>>(mvb, ctxb, L);
    attn_top_kernel<<<64 * NSAMP, 256, 0, stream>>>(qb, kb, vb, topb, ctxb, L);
    // O projection -> t5 ; x1 = LN(h + attn_out) -> ctxb
    if (BL >= 8192)
      gemm_kernel<128, 0, 0><<<dim3(8, BL / 128), 256, 0, stream>>>(
          ctxb, Wo + (size_t)layer * 262144, bo + layer * 512, t5, BL, 512, 512);
    else
      gemm_kernel<64, 0, 0><<<dim3(8, BL / 64), 256, 0, stream>>>(
          ctxb, Wo + (size_t)layer * 262144, bo + layer * 512, t5, BL, 512, 512);
    res_ln_kernel<<<BL, 512, 0, stream>>>(hb, t5, ln1_g + layer * 512,
                                          ln1_b + layer * 512, ctxb);
    // FFN, chunked at M=4096; mid = qb region (32MB spans qb+kb, both dead)
    for (int r0 = 0; r0 < BL; r0 += 4096) {
      int CM = (BL - r0 < 4096) ? (BL - r0) : 4096;
      gemm_kernel<128, 1, 0><<<dim3(32, CM / 128), 256, 0, stream>>>(
          ctxb + (size_t)r0 * 512, w1 + (size_t)layer * 1048576,
          b1 + layer * 2048, qb, CM, 2048, 512);
      gemm_kernel<64, 0, 0><<<dim3(8, CM / 64), 256, 0, stream>>>(
          qb, w2 + (size_t)layer * 1048576, b2 + layer * 512,
          t5 + (size_t)r0 * 512, CM, 512, 2048);
    }
    // x2 = LN(x1 + y) -> hb
    res_ln_kernel<<<BL, 512, 0, stream>>>(ctxb, t5, ln2_g + layer * 512,
                                          ln2_b + layer * 512, hb);
  };

  // Stage 1+2: token embedding + LN + (2h + PE)
  token_embed_kernel<<<NBATCH * 1024, 512, 0, stream>>>(x, tok_k, tok_b, tok_g,
                                                        tok_be, hb);
  // Encoder layer 0 (L=1024)
  enc_layer(0, 1024);
  // Distilling: conv1d(k=3,512->512)+bias -> qb ; ELU(maxpool) -> hb [8,512,512]
  gemm_kernel<128, 0, 1><<<dim3(8, 64), 256, 0, stream>>>(hb, dconv_k, dconv_b,
                                                          qb, 8192, 512, 1536);
  elu_pool_kernel<<<(NBATCH * 512 * DMODEL) / 256, 256, 0, stream>>>(qb, hb,
                                                                     1024);
  // Encoder layer 1 (L=512)
  enc_layer(1, 512);
  // Final LayerNorm -> d_out
  res_ln_kernel<<<NBATCH * 512, 512, 0, stream>>>(hb, nullptr, nf_g, nf_b,
                                                  (float*)d_out);
}